// Round 1
// baseline (533.030 us; speedup 1.0000x reference)
//
#include <hip/hip_runtime.h>
#include <math.h>

// Fused: per-block 48x48 linear -> (permutation == block re-assembly) ->
// conv1(3->10,5x5)+pool+relu -> conv2(10->20,5x5)+pool+relu -> fc1+relu -> fc2 -> log_softmax
// One workgroup (256 threads) per batch element. All intermediates in LDS.

__global__ __launch_bounds__(256, 4)
void fused_net(const float* __restrict__ x,    // [B,32,32,3] NHWC
               const float* __restrict__ W,    // [48,48]
               const float* __restrict__ w1,   // [10,3,5,5]
               const float* __restrict__ b1,   // [10]
               const float* __restrict__ w2,   // [20,10,5,5]
               const float* __restrict__ b2,   // [20]
               const float* __restrict__ fw1,  // [50,500]
               const float* __restrict__ fb1,  // [50]
               const float* __restrict__ fw2,  // [10,50]
               const float* __restrict__ fb2,  // [10]
               float* __restrict__ out)        // [B,10]
{
    const int b   = blockIdx.x;
    const int tid = threadIdx.x;

    // LDS: padded strides for bank spread, 16B alignment for b128 access
    __shared__ __align__(16) float s_img[3 * 1152];   // [c][i][j], stride 36 (36*4B %16==0)
    __shared__ __align__(16) float s_h1[10 * 224];    // [oc][oi*16+oj], 14x14 valid
    __shared__ __align__(16) float s_c2[2000];        // [oc][ci*10+cj], 20x10x10
    __shared__ __align__(16) float s_h2[500];         // pooled conv2, flatten order oc*25+oi*5+oj
    __shared__ __align__(16) float s_f1[50];
    __shared__ __align__(16) float s_lg[10];

    const int wave = __builtin_amdgcn_readfirstlane(tid >> 6);  // uniform wave id -> SGPR weight loads
    const int lane = tid & 63;

    // ---------------- Phase 1: per-block 48x48 linear -> s_img (NCHW) ----------------
    // lane = block (bi,bj); its 48 inputs cached in VGPRs; wave w handles k'-groups g=3w..3w+2,
    // g=(di*3+c); for each group the 4 dj outputs are one aligned float4 LDS write.
    {
        const int bi = lane >> 3, bj = lane & 7;
        const float* xb = x + (size_t)b * 3072 + bi * 384 + bj * 12;
        float xv[48];
        #pragma unroll
        for (int d = 0; d < 4; ++d) {
            const float4 a0 = *reinterpret_cast<const float4*>(xb + d * 96 + 0);
            const float4 a1 = *reinterpret_cast<const float4*>(xb + d * 96 + 4);
            const float4 a2 = *reinterpret_cast<const float4*>(xb + d * 96 + 8);
            xv[d*12+ 0] = a0.x; xv[d*12+ 1] = a0.y; xv[d*12+ 2] = a0.z; xv[d*12+ 3] = a0.w;
            xv[d*12+ 4] = a1.x; xv[d*12+ 5] = a1.y; xv[d*12+ 6] = a1.z; xv[d*12+ 7] = a1.w;
            xv[d*12+ 8] = a2.x; xv[d*12+ 9] = a2.y; xv[d*12+10] = a2.z; xv[d*12+11] = a2.w;
        }
        for (int gg = 0; gg < 3; ++gg) {
            const int g  = wave * 3 + gg;     // uniform
            const int di = g / 3, c = g % 3;  // uniform
            float acc[4] = {0.f, 0.f, 0.f, 0.f};
            #pragma unroll
            for (int dj = 0; dj < 4; ++dj) {
                const int kp = di * 12 + dj * 3 + c;       // uniform row of W
                const float* wr = W + kp * 48;
                #pragma unroll
                for (int k = 0; k < 48; ++k) acc[dj] += wr[k] * xv[k];
            }
            float4 v; v.x = acc[0]; v.y = acc[1]; v.z = acc[2]; v.w = acc[3];
            *reinterpret_cast<float4*>(&s_img[c * 1152 + (bi * 4 + di) * 36 + bj * 4]) = v;
        }
    }
    __syncthreads();

    // ---------------- Phase 2: conv1 5x5 + bias, maxpool 2x2, relu -> s_h1 ----------------
    // thread = pooled pixel (196 of them); 10 oc accumulators share each img read.
    if (tid < 196) {
        const int oi = tid / 14, oj = tid % 14;
        float mx[10];
        #pragma unroll
        for (int o = 0; o < 10; ++o) mx[o] = -1e30f;
        for (int pi = 0; pi < 2; ++pi)
        for (int pj = 0; pj < 2; ++pj) {
            const int ci = 2 * oi + pi, cj = 2 * oj + pj;
            float acc[10];
            #pragma unroll
            for (int o = 0; o < 10; ++o) acc[o] = b1[o];
            for (int ic = 0; ic < 3; ++ic) {
                #pragma unroll
                for (int ky = 0; ky < 5; ++ky)
                #pragma unroll
                for (int kx = 0; kx < 5; ++kx) {
                    const float v = s_img[ic * 1152 + (ci + ky) * 36 + (cj + kx)];
                    const float* wp = w1 + (ic * 25 + ky * 5 + kx);   // uniform
                    #pragma unroll
                    for (int o = 0; o < 10; ++o) acc[o] += v * wp[o * 75];
                }
            }
            #pragma unroll
            for (int o = 0; o < 10; ++o) mx[o] = fmaxf(mx[o], acc[o]);
        }
        #pragma unroll
        for (int o = 0; o < 10; ++o) s_h1[o * 224 + oi * 16 + oj] = fmaxf(mx[o], 0.f);
    }
    __syncthreads();

    // ---------------- Phase 3: conv2 5x5 + bias -> s_c2 (pre-pool) ----------------
    // wave w owns ocs 5w..5w+4 (uniform); lane covers conv pixels lane and lane+64.
    {
        const int p0 = lane;
        const int p1 = lane + 64;
        const bool has1 = (p1 < 100);
        const int p1v = has1 ? p1 : 0;
        const int ci0 = p0 / 10, cj0 = p0 % 10;
        const int ci1 = p1v / 10, cj1 = p1v % 10;
        float acc0[5], acc1[5];
        #pragma unroll
        for (int o = 0; o < 5; ++o) { acc0[o] = b2[wave * 5 + o]; acc1[o] = acc0[o]; }
        for (int ic = 0; ic < 10; ++ic) {
            #pragma unroll
            for (int ky = 0; ky < 5; ++ky)
            #pragma unroll
            for (int kx = 0; kx < 5; ++kx) {
                float wv[5];
                #pragma unroll
                for (int o = 0; o < 5; ++o)
                    wv[o] = w2[(wave * 5 + o) * 250 + ic * 25 + ky * 5 + kx];  // uniform
                const float v0 = s_h1[ic * 224 + (ci0 + ky) * 16 + (cj0 + kx)];
                const float v1 = s_h1[ic * 224 + (ci1 + ky) * 16 + (cj1 + kx)];
                #pragma unroll
                for (int o = 0; o < 5; ++o) { acc0[o] += v0 * wv[o]; acc1[o] += v1 * wv[o]; }
            }
        }
        #pragma unroll
        for (int o = 0; o < 5; ++o) {
            s_c2[(wave * 5 + o) * 100 + p0] = acc0[o];
            if (has1) s_c2[(wave * 5 + o) * 100 + p1] = acc1[o];
        }
    }
    __syncthreads();

    // ---------------- Phase 4: maxpool 2x2 + relu -> s_h2 (flatten order) ----------------
    for (int idx = tid; idx < 500; idx += 256) {
        const int oc = idx / 25, r = idx % 25, oi = r / 5, oj = r % 5;
        const float* p = &s_c2[oc * 100 + (2 * oi) * 10 + 2 * oj];
        const float v = fmaxf(fmaxf(p[0], p[1]), fmaxf(p[10], p[11]));
        s_h2[idx] = fmaxf(v, 0.f);
    }
    __syncthreads();

    // ---------------- Phase 5: fc1 (500->50) + relu ----------------
    if (tid < 50) {
        const float* wr = fw1 + tid * 500;
        float acc = fb1[tid];
        for (int i = 0; i < 125; ++i) {
            const float4 wv = *reinterpret_cast<const float4*>(wr + i * 4);
            const float4 hv = *reinterpret_cast<const float4*>(&s_h2[i * 4]);
            acc += wv.x * hv.x + wv.y * hv.y + wv.z * hv.z + wv.w * hv.w;
        }
        s_f1[tid] = fmaxf(acc, 0.f);
    }
    __syncthreads();

    // ---------------- Phase 6: fc2 (50->10) ----------------
    if (tid < 10) {
        const float* wr = fw2 + tid * 50;
        float acc = fb2[tid];
        for (int k = 0; k < 50; ++k) acc += s_f1[k] * wr[k];
        s_lg[tid] = acc;
    }
    __syncthreads();

    // ---------------- Phase 7: log_softmax, write out ----------------
    if (tid < 10) {
        float m = s_lg[0];
        for (int k = 1; k < 10; ++k) m = fmaxf(m, s_lg[k]);
        float s = 0.f;
        for (int k = 0; k < 10; ++k) s += expf(s_lg[k] - m);
        out[(size_t)b * 10 + tid] = s_lg[tid] - m - logf(s);
    }
}

extern "C" void kernel_launch(void* const* d_in, const int* in_sizes, int n_in,
                              void* d_out, int out_size, void* d_ws, size_t ws_size,
                              hipStream_t stream) {
    const float* x   = (const float*)d_in[0];
    const float* W   = (const float*)d_in[1];
    const float* w1  = (const float*)d_in[2];
    const float* b1  = (const float*)d_in[3];
    const float* w2  = (const float*)d_in[4];
    const float* b2  = (const float*)d_in[5];
    const float* fw1 = (const float*)d_in[6];
    const float* fb1 = (const float*)d_in[7];
    const float* fw2 = (const float*)d_in[8];
    const float* fb2 = (const float*)d_in[9];
    float* o = (float*)d_out;

    const int B = in_sizes[0] / 3072;
    fused_net<<<dim3(B), dim3(256), 0, stream>>>(x, W, w1, b1, w2, b2, fw1, fb1, fw2, fb2, o);
}

// Round 2
// 357.885 us; speedup vs baseline: 1.4894x; 1.4894x over previous
//
#include <hip/hip_runtime.h>
#include <math.h>

// Fused: per-block 48x48 linear -> (permutation == block re-assembly) ->
// conv1(3->10,5x5)+pool+relu -> conv2(10->20,5x5)+pool+relu -> fc1+relu -> fc2 -> log_softmax
// One workgroup (256 threads) per batch element. All intermediates in LDS.
// Round 2: register-window convs (rows streamed through VGPRs, 3x ds_read_b64 per row,
// all FMAs constant-indexed), conv2 pool fused via lane-half split + shfl,
// padded LDS strides (38 / 18) for bank spread.

#define S1 38               // s_img row stride (floats), row plane = 32*S1
#define S2 18               // s_h1 row stride (floats), plane = 14*S2

__global__ __launch_bounds__(256, 5)
void fused_net(const float* __restrict__ x,    // [B,32,32,3] NHWC
               const float* __restrict__ W,    // [48,48]
               const float* __restrict__ w1,   // [10,3,5,5]
               const float* __restrict__ b1,   // [10]
               const float* __restrict__ w2,   // [20,10,5,5]
               const float* __restrict__ b2,   // [20]
               const float* __restrict__ fw1,  // [50,500]
               const float* __restrict__ fb1,  // [50]
               const float* __restrict__ fw2,  // [10,50]
               const float* __restrict__ fb2,  // [10]
               float* __restrict__ out)        // [B,10]
{
    const int b   = blockIdx.x;
    const int tid = threadIdx.x;
    const int wave = __builtin_amdgcn_readfirstlane(tid >> 6);  // uniform -> SGPR weight loads
    const int lane = tid & 63;

    __shared__ __align__(16) float s_img[3 * 32 * S1];   // 14592 B
    __shared__ __align__(16) float s_h1[10 * 14 * S2];   // 10080 B
    __shared__ __align__(16) float s_h2[500];            // pooled conv2 (flatten order)
    __shared__ __align__(16) float s_part[256];          // fc1 partials
    __shared__ __align__(16) float s_f1[56];
    __shared__ __align__(16) float s_lg[16];

    // ---------------- Phase 1: per-block 48x48 linear -> s_img (NCHW) ----------------
    {
        const int bi = lane >> 3, bj = lane & 7;
        const float* xb = x + (size_t)b * 3072 + bi * 384 + bj * 12;
        float xv[48];
        #pragma unroll
        for (int d = 0; d < 4; ++d) {
            const float4 a0 = *reinterpret_cast<const float4*>(xb + d * 96 + 0);
            const float4 a1 = *reinterpret_cast<const float4*>(xb + d * 96 + 4);
            const float4 a2 = *reinterpret_cast<const float4*>(xb + d * 96 + 8);
            xv[d*12+ 0] = a0.x; xv[d*12+ 1] = a0.y; xv[d*12+ 2] = a0.z; xv[d*12+ 3] = a0.w;
            xv[d*12+ 4] = a1.x; xv[d*12+ 5] = a1.y; xv[d*12+ 6] = a1.z; xv[d*12+ 7] = a1.w;
            xv[d*12+ 8] = a2.x; xv[d*12+ 9] = a2.y; xv[d*12+10] = a2.z; xv[d*12+11] = a2.w;
        }
        for (int gg = 0; gg < 3; ++gg) {
            const int g  = wave * 3 + gg;     // uniform; g = di*3 + c
            const int di = g / 3, c = g % 3;
            float acc[4] = {0.f, 0.f, 0.f, 0.f};
            #pragma unroll
            for (int dj = 0; dj < 4; ++dj) {
                const int kp = di * 12 + dj * 3 + c;       // uniform row of W
                const float* wr = W + kp * 48;
                #pragma unroll
                for (int k = 0; k < 48; ++k) acc[dj] += wr[k] * xv[k];
            }
            float* dst = &s_img[c * (32 * S1) + (bi * 4 + di) * S1 + bj * 4];
            float2 v0; v0.x = acc[0]; v0.y = acc[1];
            float2 v1; v1.x = acc[2]; v1.y = acc[3];
            *reinterpret_cast<float2*>(dst)     = v0;
            *reinterpret_cast<float2*>(dst + 2) = v1;
        }
    }
    __syncthreads();

    // ---------------- Phase 2: conv1 + maxpool + relu -> s_h1 ----------------
    // thread = pooled pixel; rows streamed through a 6-float register window.
    if (tid < 196) {
        const int oi = tid / 14, oj = tid % 14;
        float acc[2][2][10];   // [pi][pj][oc]
        #pragma unroll
        for (int pi = 0; pi < 2; ++pi)
            #pragma unroll
            for (int pj = 0; pj < 2; ++pj)
                #pragma unroll
                for (int o = 0; o < 10; ++o) acc[pi][pj][o] = 0.f;

        const int rbase = (2 * oi) * S1 + 2 * oj;
        for (int ic = 0; ic < 3; ++ic) {
            const float* ip = s_img + ic * (32 * S1) + rbase;
            #pragma unroll
            for (int d = 0; d < 6; ++d) {                  // input row = 2*oi + d
                float wnd[6];
                const float2 r0 = *reinterpret_cast<const float2*>(ip + d * S1 + 0);
                const float2 r1 = *reinterpret_cast<const float2*>(ip + d * S1 + 2);
                const float2 r2 = *reinterpret_cast<const float2*>(ip + d * S1 + 4);
                wnd[0] = r0.x; wnd[1] = r0.y; wnd[2] = r1.x; wnd[3] = r1.y; wnd[4] = r2.x; wnd[5] = r2.y;
                #pragma unroll
                for (int pi = 0; pi < 2; ++pi) {
                    const int ky = d - pi;
                    if (ky < 0 || ky > 4) continue;
                    #pragma unroll
                    for (int kx = 0; kx < 5; ++kx) {
                        float wv[10];
                        #pragma unroll
                        for (int o = 0; o < 10; ++o)
                            wv[o] = w1[o * 75 + ic * 25 + ky * 5 + kx];   // uniform -> SGPR
                        #pragma unroll
                        for (int pj = 0; pj < 2; ++pj)
                            #pragma unroll
                            for (int o = 0; o < 10; ++o)
                                acc[pi][pj][o] += wnd[pj + kx] * wv[o];
                    }
                }
            }
        }
        #pragma unroll
        for (int o = 0; o < 10; ++o) {
            float m = fmaxf(fmaxf(acc[0][0][o], acc[0][1][o]), fmaxf(acc[1][0][o], acc[1][1][o]));
            s_h1[o * (14 * S2) + oi * S2 + oj] = fmaxf(m + b1[o], 0.f);
        }
    }
    __syncthreads();

    // ---------------- Phase 3: conv2 + maxpool + relu -> s_h2 ----------------
    // wave w owns ocs 5w..5w+4 (uniform). lane<50: h=lane/25 picks conv-row half (pi=h),
    // p=lane%25 is the pooled pixel. Each lane does the FULL ic sum for its 2 conv pixels.
    if (lane < 50) {
        const int h = lane / 25, p = lane - 25 * h;
        const int oi = p / 5, oj = p - 5 * oi;
        float acc[2][5];   // [pj][oc]
        #pragma unroll
        for (int pj = 0; pj < 2; ++pj)
            #pragma unroll
            for (int o = 0; o < 5; ++o) acc[pj][o] = 0.f;

        const int rbase = (2 * oi + h) * S2 + 2 * oj;
        for (int ic = 0; ic < 10; ++ic) {
            const float* ip = s_h1 + ic * (14 * S2) + rbase;
            #pragma unroll
            for (int ky = 0; ky < 5; ++ky) {
                float wnd[6];
                const float2 r0 = *reinterpret_cast<const float2*>(ip + ky * S2 + 0);
                const float2 r1 = *reinterpret_cast<const float2*>(ip + ky * S2 + 2);
                const float2 r2 = *reinterpret_cast<const float2*>(ip + ky * S2 + 4);
                wnd[0] = r0.x; wnd[1] = r0.y; wnd[2] = r1.x; wnd[3] = r1.y; wnd[4] = r2.x; wnd[5] = r2.y;
                #pragma unroll
                for (int kx = 0; kx < 5; ++kx) {
                    float wv[5];
                    #pragma unroll
                    for (int o = 0; o < 5; ++o)
                        wv[o] = w2[(wave * 5 + o) * 250 + ic * 25 + ky * 5 + kx]; // uniform
                    #pragma unroll
                    for (int pj = 0; pj < 2; ++pj)
                        #pragma unroll
                        for (int o = 0; o < 5; ++o)
                            acc[pj][o] += wnd[pj + kx] * wv[o];
                }
            }
        }
        // pool over pj within lane, over pi via lane-half shuffle; bias after max (monotone).
        #pragma unroll
        for (int o = 0; o < 5; ++o) {
            const float pm = fmaxf(acc[0][o], acc[1][o]);
            const float om = __shfl(pm, lane + 25, 64);
            if (lane < 25) {
                const float v = fmaxf(pm, om) + b2[wave * 5 + o];
                s_h2[(wave * 5 + o) * 25 + p] = fmaxf(v, 0.f);
            }
        }
    }
    __syncthreads();

    // ---------------- Phase 4: fc1 (500->50) split 5-way + relu ----------------
    if (tid < 250) {
        const int oc = tid / 5, part = tid % 5;
        const float* wr = fw1 + oc * 500 + part * 100;
        const float* hp = s_h2 + part * 100;
        float a = 0.f;
        #pragma unroll
        for (int i = 0; i < 25; ++i) {
            const float4 wv = *reinterpret_cast<const float4*>(wr + i * 4);
            const float4 hv = *reinterpret_cast<const float4*>(hp + i * 4);
            a += wv.x * hv.x + wv.y * hv.y + wv.z * hv.z + wv.w * hv.w;
        }
        s_part[tid] = a;
    }
    __syncthreads();
    if (tid < 50) {
        float a = fb1[tid];
        #pragma unroll
        for (int j = 0; j < 5; ++j) a += s_part[tid * 5 + j];
        s_f1[tid] = fmaxf(a, 0.f);
    }
    __syncthreads();

    // ---------------- Phase 5: fc2 (50->10) ----------------
    if (tid < 10) {
        const float* wr = fw2 + tid * 50;
        float a = fb2[tid];
        for (int k = 0; k < 50; ++k) a += s_f1[k] * wr[k];
        s_lg[tid] = a;
    }
    __syncthreads();

    // ---------------- Phase 6: log_softmax ----------------
    if (tid < 10) {
        float m = s_lg[0];
        for (int k = 1; k < 10; ++k) m = fmaxf(m, s_lg[k]);
        float s = 0.f;
        for (int k = 0; k < 10; ++k) s += expf(s_lg[k] - m);
        out[(size_t)b * 10 + tid] = s_lg[tid] - m - logf(s);
    }
}

extern "C" void kernel_launch(void* const* d_in, const int* in_sizes, int n_in,
                              void* d_out, int out_size, void* d_ws, size_t ws_size,
                              hipStream_t stream) {
    const float* x   = (const float*)d_in[0];
    const float* W   = (const float*)d_in[1];
    const float* w1  = (const float*)d_in[2];
    const float* b1  = (const float*)d_in[3];
    const float* w2  = (const float*)d_in[4];
    const float* b2  = (const float*)d_in[5];
    const float* fw1 = (const float*)d_in[6];
    const float* fb1 = (const float*)d_in[7];
    const float* fw2 = (const float*)d_in[8];
    const float* fb2 = (const float*)d_in[9];
    float* o = (float*)d_out;

    const int B = in_sizes[0] / 3072;
    fused_net<<<dim3(B), dim3(256), 0, stream>>>(x, W, w1, b1, w2, b2, fw1, fb1, fw2, fb2, o);
}